// Round 6
// baseline (182.367 us; speedup 1.0000x reference)
//
#include <hip/hip_runtime.h>
#include <hip/hip_bf16.h>
#include <stdint.h>

#define BATCH 256
#define PFD 128
#define T1 129
#define NPAIRS 1089      // 33*33
#define BKSTR 72         // u16 stride per n-row inside a 64-k LDS tile (144 B)
#define TILEW (PFD * BKSTR)
#define CHUNK 8
#define AVSTR 9          // av_lds row stride (floats), odd -> spread banks
#define SMAX 512

typedef short bf16x8 __attribute__((ext_vector_type(8)));
typedef float f32x4 __attribute__((ext_vector_type(4)));

static __device__ __forceinline__ float float_of(unsigned u){ union{float f;unsigned u;}x;x.u=u;return x.f; }
static __device__ __forceinline__ unsigned pk_bf16(float a, float b){
  union { __hip_bfloat162 h; unsigned u; } c;
  c.h = __float22bfloat162_rn(make_float2(a, b));
  return c.u;
}

// ---------------- Kernel 1: split-K fused trilinear GEMM ----------------
// MFMA k-slot q of pair p maps to W1 row (q+1)%129: slots 0..127 -> rows 1..128
// (t-value = text[q], aligned!), tail slot -> row 0 (t = 1).
// Wave org: wave w covers m = (w&3)*64..+63 (4 mt), n = (w>>2)*64..+63 (4 nt).
// A = bf16(av * t) built from global text (L1/L2-hot); W1 64-row tiles staged
// to LDS dbuf via per-thread column gather; ONE barrier per tile; 2 blocks/CU.
__global__ __launch_bounds__(512, 4) void tfn_k1(
    const float* __restrict__ audio, const float* __restrict__ video,
    const float* __restrict__ text, const float* __restrict__ W1,
    unsigned short* __restrict__ part, int S) {
  __shared__ __align__(16) short b_lds[2][TILEW];        // 36864 B
  __shared__ float av_lds[BATCH * AVSTR];                //  9216 B
  __shared__ unsigned tpk[4 * PFD];                      //  2048 B

  const int tid = threadIdx.x;
  const int bk = blockIdx.x;
  const int npb = NPAIRS / S, rem0 = NPAIRS % S;
  const int p0 = bk * npb + (bk < rem0 ? bk : rem0);
  const int np = npb + (bk < rem0 ? 1 : 0);

  const int wave = tid >> 6, lane = tid & 63;
  const int l15 = lane & 15, quad = lane >> 4;
  const int sn = tid & 127, skg = tid >> 7;
  const int mrow0 = (wave & 3) * 64, nseg = (wave >> 2) * 64;

  f32x4 acc[4][4];
  #pragma unroll
  for (int a = 0; a < 4; ++a)
    #pragma unroll
    for (int b = 0; b < 4; ++b) acc[a][b] = f32x4{0.f, 0.f, 0.f, 0.f};

  float pf[16];

  for (int c0 = 0; c0 < np; c0 += CHUNK) {
    const int nc = (np - c0) < CHUNK ? (np - c0) : CHUNK;
    const int pbase = p0 + c0;
    __syncthreads();   // protect av/tpk rewrite from previous chunk's readers
    if (tid < BATCH) {
      const int m = tid;
      #pragma unroll
      for (int j = 0; j < CHUNK; ++j) {
        float avv = 0.0f;
        if (j < nc) {
          int p = pbase + j;
          int ia = p / 33, iv = p - ia * 33;
          float a = (ia == 0) ? 1.0f : audio[m * 32 + ia - 1];
          float v = (iv == 0) ? 1.0f : video[m * 32 + iv - 1];
          avv = a * v;
        }
        av_lds[m * AVSTR + j] = avv;
      }
    }
    {  // tail strip: bf16(W1 row it=0) of the chunk's pairs, k-pair packed
      const int d = tid >> 7, n = tid & 127;
      const int j0 = 2 * d, j1 = 2 * d + 1;
      float v0 = (j0 < nc) ? W1[(size_t)(pbase + j0) * T1 * PFD + n] : 0.0f;
      float v1 = (j1 < nc) ? W1[(size_t)(pbase + j1) * T1 * PFD + n] : 0.0f;
      tpk[d * PFD + n] = pk_bf16(v0, v1);
    }
    // prime pf: tile 0 = pair pbase, W1 rows 1..64
    {
      const size_t rb = (size_t)pbase * T1 + 1;
      #pragma unroll
      for (int g = 0; g < 2; ++g)
        #pragma unroll
        for (int j = 0; j < 8; ++j)
          pf[g * 8 + j] = W1[(rb + g * 32 + skg * 8 + j) * PFD + sn];
    }
    __syncthreads();   // av + tpk visible
    const int ntiles = nc * 2;
    for (int s = 0; s < ntiles; ++s) {
      const int buf = s & 1;
      const int sp = s >> 1, h = s & 1;
      {  // stage tile s from pf (drained at previous barrier)
        union { bf16x8 v; unsigned u[4]; } w0, w1;
        #pragma unroll
        for (int d = 0; d < 4; ++d) {
          w0.u[d] = pk_bf16(pf[2 * d], pf[2 * d + 1]);
          w1.u[d] = pk_bf16(pf[8 + 2 * d], pf[8 + 2 * d + 1]);
        }
        *(bf16x8*)&b_lds[buf][sn * BKSTR + skg * 8] = w0.v;
        *(bf16x8*)&b_lds[buf][sn * BKSTR + 32 + skg * 8] = w1.v;
      }
      if (s + 1 < ntiles) {  // issue next tile's gather
        const size_t rb = (size_t)(pbase + ((s + 1) >> 1)) * T1 + 1 + ((s + 1) & 1) * 64;
        #pragma unroll
        for (int g = 0; g < 2; ++g)
          #pragma unroll
          for (int j = 0; j < 8; ++j)
            pf[g * 8 + j] = W1[(rb + g * 32 + skg * 8 + j) * PFD + sn];
      }
      __syncthreads();   // buf staged; also separates compute(s-1) from stage(s+1)
      float avv[4];
      #pragma unroll
      for (int mt = 0; mt < 4; ++mt)
        avv[mt] = av_lds[(mrow0 + mt * 16 + l15) * AVSTR + sp];
      #pragma unroll
      for (int ks2 = 0; ks2 < 2; ++ks2) {
        bf16x8 A[4];
        #pragma unroll
        for (int mt = 0; mt < 4; ++mt) {
          const int m = mrow0 + mt * 16 + l15;
          const float4 ta = *(const float4*)&text[m * PFD + h * 64 + ks2 * 32 + quad * 8];
          const float4 tb = *(const float4*)&text[m * PFD + h * 64 + ks2 * 32 + quad * 8 + 4];
          union { bf16x8 v; unsigned u[4]; } c;
          c.u[0] = pk_bf16(avv[mt] * ta.x, avv[mt] * ta.y);
          c.u[1] = pk_bf16(avv[mt] * ta.z, avv[mt] * ta.w);
          c.u[2] = pk_bf16(avv[mt] * tb.x, avv[mt] * tb.y);
          c.u[3] = pk_bf16(avv[mt] * tb.z, avv[mt] * tb.w);
          A[mt] = c.v;
        }
        #pragma unroll
        for (int nt = 0; nt < 4; ++nt) {
          bf16x8 bf = *(const bf16x8*)&b_lds[buf][(nseg + nt * 16 + l15) * BKSTR + ks2 * 32 + quad * 8];
          #pragma unroll
          for (int mt = 0; mt < 4; ++mt)
            acc[mt][nt] = __builtin_amdgcn_mfma_f32_16x16x32_bf16(A[mt], bf, acc[mt][nt], 0, 0, 0);
        }
      }
    }
    // ---- tail MFMA: k-slot j = pair idx in chunk (t = 1, W1 row it=0) ----
    {
      bf16x8 At[4];
      #pragma unroll
      for (int mt = 0; mt < 4; ++mt) {
        union { bf16x8 v; unsigned u[4]; } c;
        c.u[0] = c.u[1] = c.u[2] = c.u[3] = 0u;
        if (quad == 0) {
          const int m = mrow0 + mt * 16 + l15;
          c.u[0] = pk_bf16(av_lds[m * AVSTR + 0], av_lds[m * AVSTR + 1]);
          c.u[1] = pk_bf16(av_lds[m * AVSTR + 2], av_lds[m * AVSTR + 3]);
          c.u[2] = pk_bf16(av_lds[m * AVSTR + 4], av_lds[m * AVSTR + 5]);
          c.u[3] = pk_bf16(av_lds[m * AVSTR + 6], av_lds[m * AVSTR + 7]);
        }
        At[mt] = c.v;
      }
      #pragma unroll
      for (int nt = 0; nt < 4; ++nt) {
        union { bf16x8 v; unsigned u[4]; } bu;
        bu.u[0] = bu.u[1] = bu.u[2] = bu.u[3] = 0u;
        if (quad == 0) {
          const int n = nseg + nt * 16 + l15;
          bu.u[0] = tpk[0 * PFD + n];
          bu.u[1] = tpk[1 * PFD + n];
          bu.u[2] = tpk[2 * PFD + n];
          bu.u[3] = tpk[3 * PFD + n];
        }
        #pragma unroll
        for (int mt = 0; mt < 4; ++mt)
          acc[mt][nt] = __builtin_amdgcn_mfma_f32_16x16x32_bf16(At[mt], bu.v, acc[mt][nt], 0, 0, 0);
      }
    }
  }

  // writeback: bf16, m-major [m][S][128 phys]; phys-in-seg = l15*4 + nt
  #pragma unroll
  for (int mt = 0; mt < 4; ++mt)
    #pragma unroll
    for (int r = 0; r < 4; ++r) {
      const int m = mrow0 + mt * 16 + quad * 4 + r;
      uint2 w;
      w.x = pk_bf16(acc[mt][0][r], acc[mt][1][r]);
      w.y = pk_bf16(acc[mt][2][r], acc[mt][3][r]);
      *(uint2*)&part[((size_t)m * S + bk) * PFD + nseg + l15 * 4] = w;
    }
}

// ---------------- Kernel 2: contiguous reduce + bias/relu + layers 2,3 ----------------
__global__ __launch_bounds__(256) void tfn_k2(
    const unsigned short* __restrict__ part, const float* __restrict__ b1,
    const float* __restrict__ W2, const float* __restrict__ b2,
    const float* __restrict__ W3, const float* __restrict__ b3,
    float* __restrict__ out, int S) {
  __shared__ float sred[256 * 4];
  __shared__ float h1s[PFD];
  __shared__ float a2s[256];
  __shared__ float red[2];
  const int m = blockIdx.x, tid = threadIdx.x;
  const int g = tid & 31, q = tid >> 5;
  const unsigned short* base = part + (size_t)m * S * PFD;
  float s0 = 0, s1 = 0, s2 = 0, s3 = 0;
  for (int bkk = q; bkk < S; bkk += 8) {
    uint2 v = *(const uint2*)&base[(size_t)bkk * PFD + g * 4];
    s0 += float_of(v.x << 16);
    s1 += float_of(v.x & 0xFFFF0000u);
    s2 += float_of(v.y << 16);
    s3 += float_of(v.y & 0xFFFF0000u);
  }
  sred[tid * 4 + 0] = s0; sred[tid * 4 + 1] = s1;
  sred[tid * 4 + 2] = s2; sred[tid * 4 + 3] = s3;
  __syncthreads();
  if (tid < PFD) {
    const int p = tid;       // phys column
    float h = 0;
    #pragma unroll
    for (int bl = 0; bl < 8; ++bl) h += sred[(bl * 32 + (p >> 2)) * 4 + (p & 3)];
    const int seg = p >> 6, qq = p & 63;
    const int n = seg * 64 + (qq & 3) * 16 + (qq >> 2);   // phys -> logical
    h1s[n] = fmaxf(h + b1[n], 0.0f);
  }
  __syncthreads();
  const int n = tid & 127, half = tid >> 7;
  float a2 = 0.0f;
  const int k0 = half * 64;
  #pragma unroll 8
  for (int k = 0; k < 64; ++k) a2 += h1s[k0 + k] * W2[(k0 + k) * PFD + n];
  a2s[tid] = a2;
  __syncthreads();
  if (half == 0) {
    float h2 = fmaxf(a2s[n] + a2s[n + 128] + b2[n], 0.0f);
    float pr = h2 * W3[n];
    #pragma unroll
    for (int off = 32; off > 0; off >>= 1) pr += __shfl_down(pr, off);
    if ((tid & 63) == 0) red[tid >> 6] = pr;
  }
  __syncthreads();
  if (tid == 0) out[m] = red[0] + red[1] + b3[0];
}

extern "C" void kernel_launch(void* const* d_in, const int* in_sizes, int n_in,
                              void* d_out, int out_size, void* d_ws, size_t ws_size,
                              hipStream_t stream) {
  const float* audio = (const float*)d_in[0];
  const float* video = (const float*)d_in[1];
  const float* text  = (const float*)d_in[2];
  const float* W1 = (const float*)d_in[3];
  const float* b1 = (const float*)d_in[4];
  const float* W2 = (const float*)d_in[5];
  const float* b2 = (const float*)d_in[6];
  const float* W3 = (const float*)d_in[7];
  const float* b3 = (const float*)d_in[8];
  unsigned short* part = (unsigned short*)d_ws;

  const size_t slab = (size_t)BATCH * PFD * sizeof(unsigned short);  // 64 KB
  int S = (int)(ws_size / slab);
  if (S > SMAX) S = SMAX;
  if (S < 1) S = 1;

  tfn_k1<<<S, 512, 0, stream>>>(audio, video, text, W1, part, S);
  tfn_k2<<<BATCH, 256, 0, stream>>>(part, b1, W2, b2, W3, b3, (float*)d_out, S);
}